// Round 4
// baseline (100.212 us; speedup 1.0000x reference)
//
#include <hip/hip_runtime.h>
#include <cstdint>
#include <cstddef>

// BAP: out0[b,m,c] = (1/HW) * sum_k feat[b,c,k] * sigmoid(raw[b,m,k])
//      out1[b,m,k] = sigmoid(raw[b,m,k])
// B=16, C=1024, M=32, K=H*W=1024.
// R4: R3 was latency-bound (VALU 19%, HBM 16%, occ 15%; 2-phase with no
// overlap). Fix: T14 async-stage pipeline (loads in regs during compute,
// ds_write after barrier) + 4m x 8c thread tile (LDS 2 -> 1.5 B/FMA),
// 16-slot XOR swizzle kept exactly 2-way (free) on both write and read.

#define BB 16
#define CC 1024
#define MM 32
#define HW 1024

#define TC   256              // c-rows per block tile
#define TK   64               // k per LDS stage (16 f32x4 slots per row)
#define KSPL 8                // k-split factor (atomic combine)
#define KPB  (HW / KSPL)      // 128 k per block
#define NST  (KPB / TK)       // 2 stages

typedef __attribute__((ext_vector_type(4))) float f32x4;

// ---------------- kernel 1: sigmoid + zero out0 ----------------
__global__ __launch_bounds__(256) void sigmoid_zero_kernel(
    const float* __restrict__ raw, float* __restrict__ out0,
    float* __restrict__ out1)
{
    int i = blockIdx.x * 256 + threadIdx.x;
    f32x4 v = reinterpret_cast<const f32x4*>(raw)[i];
    f32x4 s;
#pragma unroll
    for (int j = 0; j < 4; ++j)
        s[j] = 1.0f / (1.0f + __expf(-v[j]));
    reinterpret_cast<f32x4*>(out1)[i] = s;
    reinterpret_cast<f32x4*>(out0)[i] = (f32x4){0.f, 0.f, 0.f, 0.f};
}

// ---------------- kernel 2: pipelined tiled contraction ----------------
// Grid: 512 = 16 b * 4 c-tiles * 8 k-splits; 256 threads (4 waves).
// Thread tile: 4m x 8c (c-quads at cc*4 and cc*4+128).
// feat LDS [TC][TK], f32x4-slot XOR swizzle: slot' = slot ^ ((row>>2)&15).
__global__ __launch_bounds__(256) void bap_tile2(
    const float* __restrict__ feat,   // [B][C][HW]
    const float* __restrict__ att,    // [B][M][HW]
    float* __restrict__ out0)         // [B][M][C]
{
    __shared__ float fsh[TC][TK];     // 64 KB, swizzled slots
    __shared__ float ash[MM][TK];     // 8 KB, linear

    const int t  = threadIdx.x;
    const int b  = blockIdx.x >> 5;          // 0..15
    const int ct = (blockIdx.x >> 3) & 3;    // c-tile 0..3
    const int kh = blockIdx.x & 7;           // k-split 0..7
    const int cbase = ct * TC;
    const int kbase = kh * KPB;

    const int mt = t >> 5;       // 0..7 -> m0 = 4*mt
    const int cc = t & 31;       // 0..31
    const int m0 = mt * 4;

    // staging decomposition (same for both arrays)
    const int srow_f = t >> 4;            // feat: +16 rows per step, 16 steps
    const int slot   = t & 15;            // f32x4 slot 0..15
    const int swz_f_base = slot;          // swizzle applied at write

    float4 fv[16];
    float4 av[2];

    const float* fp = feat + (size_t)(b * CC + cbase) * HW + kbase;
    const float* ap = att  + (size_t)(b * MM) * HW + kbase;

    auto load_stage = [&](int s) {
        const int k0 = s * TK;
#pragma unroll
        for (int i = 0; i < 16; ++i) {
            int row = srow_f + i * 16;
            fv[i] = *reinterpret_cast<const float4*>(
                fp + (size_t)row * HW + k0 + slot * 4);
        }
#pragma unroll
        for (int i = 0; i < 2; ++i) {
            int row = srow_f + i * 16;    // 0..31
            av[i] = *reinterpret_cast<const float4*>(
                ap + (size_t)row * HW + k0 + slot * 4);
        }
    };

    auto write_stage = [&]() {
#pragma unroll
        for (int i = 0; i < 16; ++i) {
            int row = srow_f + i * 16;
            int sw  = swz_f_base ^ ((row >> 2) & 15);
            *reinterpret_cast<float4*>(&fsh[row][sw * 4]) = fv[i];
        }
#pragma unroll
        for (int i = 0; i < 2; ++i) {
            int row = srow_f + i * 16;
            *reinterpret_cast<float4*>(&ash[row][slot * 4]) = av[i];
        }
    };

    float acc[4][8] = {};

    auto compute = [&]() {
#pragma unroll 4
        for (int g = 0; g < 16; ++g) {
            f32x4 a[4], f[8];
#pragma unroll
            for (int i = 0; i < 4; ++i)
                a[i] = *reinterpret_cast<const f32x4*>(&ash[m0 + i][g * 4]);
#pragma unroll
            for (int q = 0; q < 2; ++q)
#pragma unroll
                for (int jj = 0; jj < 4; ++jj) {
                    int row = q * 128 + cc * 4 + jj;
                    int sw  = g ^ ((row >> 2) & 15);
                    f[q * 4 + jj] =
                        *reinterpret_cast<const f32x4*>(&fsh[row][sw * 4]);
                }
#pragma unroll
            for (int i = 0; i < 4; ++i)
#pragma unroll
                for (int j = 0; j < 8; ++j)
#pragma unroll
                    for (int x = 0; x < 4; ++x)
                        acc[i][j] += a[i][x] * f[j][x];
        }
    };

    // ---- pipeline: stage0; {load1 | compute0}; write1; compute1 ----
    load_stage(0);
    write_stage();
    __syncthreads();

    load_stage(1);        // in flight during compute of stage 0
    compute();
    __syncthreads();      // all waves done reading fsh/ash
    write_stage();
    __syncthreads();
    compute();

    // ---- epilogue: atomic combine over k-splits ----
    const float sc = 1.0f / (float)HW;
    float* obase = out0 + (size_t)b * MM * CC + cbase;
#pragma unroll
    for (int i = 0; i < 4; ++i)
#pragma unroll
        for (int q = 0; q < 2; ++q)
#pragma unroll
            for (int jj = 0; jj < 4; ++jj)
                atomicAdd(obase + (size_t)(m0 + i) * CC + q * 128 + cc * 4 + jj,
                          acc[i][q * 4 + jj] * sc);
}

extern "C" void kernel_launch(void* const* d_in, const int* in_sizes, int n_in,
                              void* d_out, int out_size, void* d_ws, size_t ws_size,
                              hipStream_t stream)
{
    const float* feat = (const float*)d_in[0];   // [16,1024,32,32]
    const float* raw  = (const float*)d_in[1];   // [16,32,32,32]
    float* out0 = (float*)d_out;                           // [16,32,1024]
    float* out1 = out0 + (size_t)BB * MM * HW;             // [16,32,32,32]

    sigmoid_zero_kernel<<<512, 256, 0, stream>>>(raw, out0, out1);
    // 16 b * 4 c-tiles * 8 k-splits = 512 blocks
    bap_tile2<<<512, 256, 0, stream>>>(feat, out1, out0);
}

// Round 5
// 36.530 us; speedup vs baseline: 2.7433x; 2.7433x over previous
//
#include <hip/hip_runtime.h>
#include <cstdint>
#include <cstddef>

// BAP: out0[b,m,c] = (1/HW) * sum_k feat[b,c,k] * sigmoid(raw[b,m,k])
//      out1[b,m,k] = sigmoid(raw[b,m,k])
// B=16, C=1024, M=32, K=H*W=1024.
// R5: R4 failed on (a) atomic write amplification at KSPL=8 (WRITE 130MB) and
// (b) register-staged pipeline defeated by VGPR pressure (compiler sank the
// loads). Fix: global_load_lds (zero-VGPR staging, T3 2-phase dbuf pipeline),
// source-side XOR swizzle (rule #21), KSPL=4 partials to d_ws + reduce kernel
// (no atomics).

#define BB 16
#define CC 1024
#define MM 32
#define HW 1024

#define TC   128              // c-rows per block tile
#define TK   64               // k per LDS stage (16 f32x4 slots per row)
#define KSPL 4                // k-split factor
#define KPB  (HW / KSPL)      // 256 k per block
#define NST  (KPB / TK)       // 4 stages

typedef __attribute__((ext_vector_type(4))) float f32x4;

// ---------------- kernel 1: sigmoid (+ optional zero of out0) ----------------
__global__ __launch_bounds__(256) void sigmoid_kernel(
    const float* __restrict__ raw, float* __restrict__ out1,
    float* zero_me)
{
    int i = blockIdx.x * 256 + threadIdx.x;
    f32x4 v = reinterpret_cast<const f32x4*>(raw)[i];
    f32x4 s;
#pragma unroll
    for (int j = 0; j < 4; ++j)
        s[j] = 1.0f / (1.0f + __expf(-v[j]));
    reinterpret_cast<f32x4*>(out1)[i] = s;
    if (zero_me)
        reinterpret_cast<f32x4*>(zero_me)[i] = (f32x4){0.f, 0.f, 0.f, 0.f};
}

// async global->LDS, 16B per lane, wave-uniform LDS base (HW: base + lane*16)
__device__ inline void gld_lds16(const float* g, float* l)
{
    __builtin_amdgcn_global_load_lds(
        (const __attribute__((address_space(1))) void*)g,
        (__attribute__((address_space(3))) void*)l, 16, 0, 0);
}

// ---------------- kernel 2: pipelined contraction ----------------
// Grid: 512 = 16 b * 8 c-tiles * 4 k-splits; 256 threads (4 waves).
// feat LDS [TC][TK] per buffer; logical layout swizzled at f32x4-slot level:
//   LDS[row][slot] holds feat[row][slot ^ ((row>>2)&15)]  (pre-swizzled
//   GLOBAL source per lane; LDS write is linear as gload_lds requires).
// Compute: thread tile 4m x 4c; feat ds_read_b128 2-way max (free),
// att reads are 2-address wave broadcasts.
template<bool USE_WS>
__global__ __launch_bounds__(256) void bap_main(
    const float* __restrict__ feat,   // [B][C][HW]
    const float* __restrict__ att,    // [B][M][HW]
    float* __restrict__ dst)          // USE_WS: partials [KSPL][B][M][C]; else out0
{
    __shared__ float fsh[2][TC][TK];  // 64 KB
    __shared__ float ash[2][MM][TK];  // 16 KB

    const int t  = threadIdx.x;
    const int w  = t >> 6;                   // wave 0..3
    const int l  = t & 63;                   // lane
    const int b  = blockIdx.x >> 5;          // 0..15
    const int ct = (blockIdx.x >> 2) & 7;    // c-tile 0..7
    const int kh = blockIdx.x & 3;           // k-split 0..3
    const int cbase = ct * TC;
    const int kbase = kh * KPB;

    const int lrow  = l >> 4;    // 0..3 (row within a 4-row gload_lds chunk)
    const int lslot = l & 15;    // f32x4 slot 0..15

    const float* fbase = feat + (size_t)(b * CC + cbase) * HW + kbase;
    const float* abase = att  + (size_t)(b * MM) * HW + kbase;

    // stage s into buffer nb: 8 feat chunks + 2 att chunks per wave,
    // each chunk = 4 rows x 16 slots = 1KB, zero VGPR data cost.
    auto stage = [&](int s, int nb) {
        const int k0 = s * TK;
#pragma unroll
        for (int i = 0; i < 8; ++i) {
            int r0  = w * 32 + i * 4;                 // wave-uniform
            int row = r0 + lrow;
            int sg  = lslot ^ ((r0 >> 2) & 15);       // source-side swizzle
            gld_lds16(fbase + (size_t)row * HW + k0 + sg * 4,
                      &fsh[nb][r0][0]);
        }
#pragma unroll
        for (int i = 0; i < 2; ++i) {
            int r0  = w * 8 + i * 4;                  // wave-uniform
            int row = r0 + lrow;
            gld_lds16(abase + (size_t)row * HW + k0 + lslot * 4,
                      &ash[nb][r0][0]);
        }
    };

    const int mt = t >> 5;       // 0..7 -> m0 = 4*mt
    const int cc = t & 31;       // 0..31 -> c-quad at cc*4
    const int m0 = mt * 4;
    const int xr = cc & 15;      // swizzle key: ((cc*4+j)>>2)&15 == cc&15

    float acc[4][4] = {};

    auto compute = [&](int nb) {
#pragma unroll 4
        for (int g = 0; g < 16; ++g) {
            f32x4 a[4], f[4];
#pragma unroll
            for (int i = 0; i < 4; ++i)
                a[i] = *reinterpret_cast<const f32x4*>(&ash[nb][m0 + i][g * 4]);
            const int sw = (g ^ xr) * 4;
#pragma unroll
            for (int j = 0; j < 4; ++j)
                f[j] = *reinterpret_cast<const f32x4*>(&fsh[nb][cc * 4 + j][sw]);
#pragma unroll
            for (int i = 0; i < 4; ++i)
#pragma unroll
                for (int j = 0; j < 4; ++j)
#pragma unroll
                    for (int x = 0; x < 4; ++x)
                        acc[i][j] += a[i][x] * f[j][x];
        }
    };

    // ---- T3-minimum pipeline: STAGE(next) -> compute(cur) -> barrier ----
    stage(0, 0);
    __syncthreads();              // drains vmcnt(0): buffer 0 ready
#pragma unroll
    for (int s = 0; s < NST; ++s) {
        if (s + 1 < NST) stage(s + 1, (s + 1) & 1);   // async, in flight
        compute(s & 1);
        __syncthreads();          // next buffer ready; cur buffer free
    }

    // ---- epilogue ----
    const float sc = 1.0f / (float)HW;
    if (USE_WS) {
        float* p = dst + (size_t)kh * (BB * MM * CC)
                 + (size_t)(b * MM) * CC + cbase + cc * 4;
#pragma unroll
        for (int i = 0; i < 4; ++i) {
            f32x4 v = { acc[i][0] * sc, acc[i][1] * sc,
                        acc[i][2] * sc, acc[i][3] * sc };
            *reinterpret_cast<f32x4*>(p + (size_t)(m0 + i) * CC) = v;
        }
    } else {
        float* p = dst + (size_t)(b * MM) * CC + cbase + cc * 4;
#pragma unroll
        for (int i = 0; i < 4; ++i)
#pragma unroll
            for (int j = 0; j < 4; ++j)
                atomicAdd(p + (size_t)(m0 + i) * CC + j, acc[i][j] * sc);
    }
}

// ---------------- kernel 3: k-split reduce (ws path) ----------------
__global__ __launch_bounds__(256) void reduce_kernel(
    const float* __restrict__ ws, float* __restrict__ out0)
{
    const int N4 = BB * MM * CC / 4;     // 131072 f32x4 elems per slice
    int i = blockIdx.x * 256 + threadIdx.x;
    const f32x4* p = reinterpret_cast<const f32x4*>(ws);
    f32x4 v = p[i];
    v += p[i + N4];
    v += p[i + 2 * N4];
    v += p[i + 3 * N4];
    reinterpret_cast<f32x4*>(out0)[i] = v;
}

extern "C" void kernel_launch(void* const* d_in, const int* in_sizes, int n_in,
                              void* d_out, int out_size, void* d_ws, size_t ws_size,
                              hipStream_t stream)
{
    const float* feat = (const float*)d_in[0];   // [16,1024,32,32]
    const float* raw  = (const float*)d_in[1];   // [16,32,32,32]
    float* out0 = (float*)d_out;                           // [16,32,1024]
    float* out1 = out0 + (size_t)BB * MM * HW;             // [16,32,32,32]

    const size_t ws_need = (size_t)KSPL * BB * MM * CC * sizeof(float); // 8 MB
    const bool use_ws = ws_size >= ws_need;

    sigmoid_kernel<<<512, 256, 0, stream>>>(raw, out1, use_ws ? nullptr : out0);

    if (use_ws) {
        bap_main<true><<<512, 256, 0, stream>>>(feat, out1, (float*)d_ws);
        reduce_kernel<<<512, 256, 0, stream>>>((const float*)d_ws, out0);
    } else {
        bap_main<false><<<512, 256, 0, stream>>>(feat, out1, out0);
    }
}